// Round 17
// baseline (58.523 us; speedup 1.0000x reference)
//
#include <hip/hip_runtime.h>
#include <hip/hip_fp16.h>

#define IN_DIM 128
#define NA 5
#define QSCALE 128.0f      // q fields 14-bit; deg counter at bit 56
#define BK 32              // nodes per bucket (idx fits bits 57..61)
#define CAP 1024           // region capacity per bucket (avg fill ~512)
#define NBLK 512           // edge slices (must equal 2*256 for offset kernel)
#define MAXNB 1600         // static LDS bound for histograms (NB=1563 at 50k nodes)

typedef __fp16 half2v __attribute__((ext_vector_type(2)));

// psd16[n]: 16 ushorts (32B): [0..4]=s0..s4 (f16), [8..12]=d0..d4+bias (f16)

__device__ __forceinline__ unsigned int pkh(float a, float b) {
    half2v h = __builtin_amdgcn_cvt_pkrtz(a, b);
    return *(unsigned int*)&h;
}
__device__ __forceinline__ float2 uph(unsigned int u) {
    __half2 h = *(__half2*)&u;
    return __half22float2(h);
}

// ---------- softmax+pack from fp16 halves ----------
__device__ __forceinline__ unsigned long long
edge_pack16(const ushort* __restrict__ psd16, int src, int dst)
{
    const uint4 sa = *(const uint4*)(psd16 + (size_t)src * 16);      // s-half (16B)
    const uint4 da = *(const uint4*)(psd16 + (size_t)dst * 16 + 8);  // d-half (16B)
    const float2 s01 = uph(sa.x), s23 = uph(sa.y), s4x = uph(sa.z);
    const float2 d01 = uph(da.x), d23 = uph(da.y), d4x = uph(da.z);

    float l[NA] = { s01.x + d01.x, s01.y + d01.y, s23.x + d23.x,
                    s23.y + d23.y, s4x.x + d4x.x };
    float mx = -INFINITY;
#pragma unroll
    for (int a = 0; a < NA; ++a) {
        l[a] = l[a] > 0.0f ? l[a] : 0.01f * l[a];   // leaky_relu(0.01)
        mx = fmaxf(mx, l[a]);
    }
    float ssum = 0.0f;
#pragma unroll
    for (int a = 0; a < NA; ++a) {
        l[a] = __expf(l[a] - mx);
        ssum += l[a];
    }
    const float inv = __frcp_rn(ssum) * QSCALE;
    const unsigned long long q0 = (unsigned long long)(unsigned int)(l[0] * inv + 0.5f);
    const unsigned long long q1 = (unsigned long long)(unsigned int)(l[1] * inv + 0.5f);
    const unsigned long long q2 = (unsigned long long)(unsigned int)(l[2] * inv + 0.5f);
    const unsigned long long q3 = (unsigned long long)(unsigned int)(l[3] * inv + 0.5f);
    return q0 | (q1 << 14) | (q2 << 28) | (q3 << 42) | (1ull << 56);
}

// ---------- A: fused per-node logits (fdot2, 16-lane groups) + bucket histogram ----------
__global__ void __launch_bounds__(256)
node_count_kernel(const float* __restrict__ x,
                  const float* __restrict__ W,
                  const float* __restrict__ b_lin,
                  const int* __restrict__ ei,
                  ushort* __restrict__ psd16,
                  unsigned int* __restrict__ cnt,   // [slice][bucket]
                  int n_nodes, int n_edges, int NB)
{
    __shared__ unsigned int h[MAXNB];
    for (int i = threadIdx.x; i < NB; i += 256) h[i] = 0u;
    __syncthreads();

    const int j = blockIdx.x;
    {
        const long long e0 = ((long long)j * n_edges) / NBLK;
        const long long e1 = ((long long)(j + 1) * n_edges) / NBLK;
        for (long long e = e0 + threadIdx.x; e < e1; e += 256) {
            int dst = ei[n_edges + e];
            dst = min(max(dst, 0), n_nodes - 1);
            atomicAdd(&h[dst >> 5], 1u);
        }
    }

    // --- node phase: 16-lane groups, lane covers dims [g*8, g*8+8), fdot2 accum ---
    {
        const int g   = threadIdx.x & 15;
        const int grp = (int)((blockIdx.x * blockDim.x + threadIdx.x) >> 4);
        const int total_g = NBLK * 16;

        half2v wh[10][4];
#pragma unroll
        for (int a = 0; a < NA; ++a) {
#pragma unroll
            for (int k = 0; k < 4; ++k) {
                const float* wr = &W[a * 2 * IN_DIM + g * 8 + 2 * k];
                wh[a][k]     = __builtin_amdgcn_cvt_pkrtz(wr[0], wr[1]);
                wh[5 + a][k] = __builtin_amdgcn_cvt_pkrtz(wr[IN_DIM], wr[IN_DIM + 1]);
            }
        }
        const float bb0 = b_lin[0], bb1 = b_lin[1], bb2 = b_lin[2], bb3 = b_lin[3], bb4 = b_lin[4];

        for (int n = grp; n < n_nodes; n += total_g) {
            const float4 xa = *(const float4*)&x[(size_t)n * IN_DIM + g * 8];
            const float4 xb = *(const float4*)&x[(size_t)n * IN_DIM + g * 8 + 4];
            half2v xh[4];
            xh[0] = __builtin_amdgcn_cvt_pkrtz(xa.x, xa.y);
            xh[1] = __builtin_amdgcn_cvt_pkrtz(xa.z, xa.w);
            xh[2] = __builtin_amdgcn_cvt_pkrtz(xb.x, xb.y);
            xh[3] = __builtin_amdgcn_cvt_pkrtz(xb.z, xb.w);

            float p[10];
#pragma unroll
            for (int a = 0; a < 10; ++a) {
                float acc = 0.0f;
#pragma unroll
                for (int k = 0; k < 4; ++k)
                    acc = __builtin_amdgcn_fdot2(xh[k], wh[a][k], acc, false);
                p[a] = acc;
            }
#pragma unroll
            for (int o = 8; o >= 1; o >>= 1) {
#pragma unroll
                for (int a = 0; a < 10; ++a) p[a] += __shfl_xor(p[a], o);
            }
            if (g == 0) {
                uint4 sa, da;
                sa.x = pkh(p[0], p[1]);
                sa.y = pkh(p[2], p[3]);
                sa.z = pkh(p[4], 0.0f);
                sa.w = 0u;
                da.x = pkh(p[5] + bb0, p[6] + bb1);
                da.y = pkh(p[7] + bb2, p[8] + bb3);
                da.z = pkh(p[9] + bb4, 0.0f);
                da.w = 0u;
                ushort* r = psd16 + (size_t)n * 16;
                *(uint4*)r       = sa;
                *(uint4*)(r + 8) = da;
            }
        }
    }

    __syncthreads();
    unsigned int* co = cnt + (size_t)j * NB;
    for (int i = threadIdx.x; i < NB; i += 256) co[i] = h[i];
}

// ---------- B: per-bucket exclusive scan over the 512 slices ----------
__global__ void __launch_bounds__(256)
offset_kernel(const unsigned int* __restrict__ cnt,
              unsigned int* __restrict__ off,
              unsigned int* __restrict__ totals, int NB)
{
    __shared__ unsigned int s[256];
    const int b = blockIdx.x;
    const int t = threadIdx.x;
    const unsigned int c0 = cnt[(size_t)(2 * t) * NB + b];
    const unsigned int c1 = cnt[(size_t)(2 * t + 1) * NB + b];
    const unsigned int pair = c0 + c1;
    s[t] = pair;
    __syncthreads();
#pragma unroll
    for (int d = 1; d < 256; d <<= 1) {
        const unsigned int v = (t >= d) ? s[t - d] : 0u;
        __syncthreads();
        s[t] += v;
        __syncthreads();
    }
    const unsigned int excl = s[t] - pair;
    const unsigned int base = (unsigned int)b * CAP;
    off[(size_t)(2 * t) * NB + b]     = base + excl;
    off[(size_t)(2 * t + 1) * NB + b] = base + excl + c0;
    if (t == 255) totals[b] = s[255];
}

// ---------- C: scatter: softmax + ONE plain u64 store per edge ----------
__global__ void __launch_bounds__(256)
scatter_kernel(const int* __restrict__ ei,
               const ushort* __restrict__ psd16,
               const unsigned int* __restrict__ off,
               unsigned long long* __restrict__ region,
               int n_edges, int n_nodes, int NB)
{
    __shared__ unsigned int o[MAXNB];
    const int j = blockIdx.x;
    const unsigned int* oj = off + (size_t)j * NB;
    for (int i = threadIdx.x; i < NB; i += 256) o[i] = oj[i];
    __syncthreads();

    const long long e0 = ((long long)j * n_edges) / NBLK;
    const long long e1 = ((long long)(j + 1) * n_edges) / NBLK;
    for (long long e = e0 + threadIdx.x; e < e1; e += 256) {
        int dst = ei[n_edges + e];
        int src = ei[e];
        dst = min(max(dst, 0), n_nodes - 1);
        src = min(max(src, 0), n_nodes - 1);
        const int b = dst >> 5;
        const unsigned int pos = atomicAdd(&o[b], 1u);   // LDS counter
        if (pos - (unsigned int)b * CAP < (unsigned int)CAP) {
            const unsigned long long p64 =
                edge_pack16(psd16, src, dst) | ((unsigned long long)(dst & 31) << 57);
            region[pos] = p64;
        }
    }
}

// ---------- D: fused reduce + finalize: one block per bucket (32 nodes) ----------
__global__ void __launch_bounds__(256)
reduce_finalize_kernel(const float* __restrict__ x,
                       const unsigned long long* __restrict__ region,
                       const unsigned int* __restrict__ totals,
                       const float* __restrict__ anchor,
                       float* __restrict__ out, int n_nodes)
{
    __shared__ float sA[NA][IN_DIM];
    __shared__ unsigned long long tab[BK];
    __shared__ float sB[BK][8];

    for (int i = threadIdx.x; i < NA * IN_DIM; i += 256)
        (&sA[0][0])[i] = anchor[i];
    if (threadIdx.x < BK) tab[threadIdx.x] = 0ull;
    __syncthreads();

    const int b = blockIdx.x;
    const unsigned int nt = min(totals[b], (unsigned int)CAP);
    const unsigned long long* rg = region + (size_t)b * CAP;
    const unsigned long long mask = 0x81FFFFFFFFFFFFFFull;   // clear idx bits 57..62
    for (unsigned int i = threadIdx.x; i < nt; i += 256) {
        const unsigned long long e = rg[i];
        atomicAdd(&tab[(unsigned int)(e >> 57) & 31u], e & mask);
    }
    __syncthreads();

    if (threadIdx.x < BK) {
        const unsigned long long s = tab[threadIdx.x];
        const float k = 1.0f / QSCALE;
        const float b0 = (float)(unsigned int)(s & 0x3FFF) * k;
        const float b1 = (float)(unsigned int)((s >> 14) & 0x3FFF) * k;
        const float b2 = (float)(unsigned int)((s >> 28) & 0x3FFF) * k;
        const float b3 = (float)(unsigned int)((s >> 42) & 0x3FFF) * k;
        const float fdeg = (float)(unsigned int)(s >> 56);
        const float b4 = fdeg - (b0 + b1 + b2 + b3);
        const float invd = 1.0f / fmaxf(fdeg, 1.0f);
        sB[threadIdx.x][0] = b0 * invd;
        sB[threadIdx.x][1] = b1 * invd;
        sB[threadIdx.x][2] = b2 * invd;
        sB[threadIdx.x][3] = b3 * invd;
        sB[threadIdx.x][4] = b4 * invd;
    }
    __syncthreads();

    // expand: 32 nodes x 32 float4 = 1024 float4, 4 per thread
    const int l = threadIdx.x & 31;
    const int c = l * 4;
#pragma unroll
    for (int it = 0; it < 4; ++it) {
        const int jn = (threadIdx.x >> 5) + it * 8;      // node within bucket
        const int n = b * BK + jn;
        if (n >= n_nodes) break;
        const float b0 = sB[jn][0], b1 = sB[jn][1], b2 = sB[jn][2],
                    b3 = sB[jn][3], b4 = sB[jn][4];
        float4 acc;
        acc.x = b0 * sA[0][c + 0] + b1 * sA[1][c + 0] + b2 * sA[2][c + 0] + b3 * sA[3][c + 0] + b4 * sA[4][c + 0];
        acc.y = b0 * sA[0][c + 1] + b1 * sA[1][c + 1] + b2 * sA[2][c + 1] + b3 * sA[3][c + 1] + b4 * sA[4][c + 1];
        acc.z = b0 * sA[0][c + 2] + b1 * sA[1][c + 2] + b2 * sA[2][c + 2] + b3 * sA[3][c + 2] + b4 * sA[4][c + 2];
        acc.w = b0 * sA[0][c + 3] + b1 * sA[1][c + 3] + b2 * sA[2][c + 3] + b3 * sA[3][c + 3] + b4 * sA[4][c + 3];

        const size_t idx = (size_t)n * (IN_DIM / 4) + l;
        const float4 xv = ((const float4*)x)[idx];
        float4 ov;
        ov.x = xv.x + acc.x;
        ov.y = xv.y + acc.y;
        ov.z = xv.z + acc.z;
        ov.w = xv.w + acc.w;
        ((float4*)out)[idx] = ov;
    }
}

// ---------- Path B fallback: packed global atomics ----------
__global__ void __launch_bounds__(256)
fill_zero_kernel(unsigned long long* __restrict__ p, size_t n)
{
    size_t i = (size_t)blockIdx.x * blockDim.x + threadIdx.x;
    const size_t stride = (size_t)gridDim.x * blockDim.x;
    for (; i < n; i += stride) p[i] = 0ull;
}

__global__ void __launch_bounds__(256)
node_logits_kernel(const float* __restrict__ x,
                   const float* __restrict__ W,
                   const float* __restrict__ b_lin,
                   ushort* __restrict__ psd16,
                   int n_nodes, int total_hw)
{
    const int l32 = threadIdx.x & 31;
    const int hw0 = (int)((blockIdx.x * blockDim.x + threadIdx.x) >> 5);
    float ws[NA][4], wd[NA][4];
#pragma unroll
    for (int a = 0; a < NA; ++a) {
        const float4 s = *(const float4*)&W[a * 2 * IN_DIM + l32 * 4];
        const float4 d = *(const float4*)&W[a * 2 * IN_DIM + IN_DIM + l32 * 4];
        ws[a][0] = s.x; ws[a][1] = s.y; ws[a][2] = s.z; ws[a][3] = s.w;
        wd[a][0] = d.x; wd[a][1] = d.y; wd[a][2] = d.z; wd[a][3] = d.w;
    }
    const float bb0 = b_lin[0], bb1 = b_lin[1], bb2 = b_lin[2], bb3 = b_lin[3], bb4 = b_lin[4];
    for (int n = hw0; n < n_nodes; n += total_hw) {
        const float4 xv = *(const float4*)&x[(size_t)n * IN_DIM + l32 * 4];
        float p[2 * NA];
#pragma unroll
        for (int a = 0; a < NA; ++a) {
            p[a]      = xv.x * ws[a][0] + xv.y * ws[a][1] + xv.z * ws[a][2] + xv.w * ws[a][3];
            p[NA + a] = xv.x * wd[a][0] + xv.y * wd[a][1] + xv.z * wd[a][2] + xv.w * wd[a][3];
        }
#pragma unroll
        for (int o = 16; o >= 1; o >>= 1) {
#pragma unroll
            for (int a = 0; a < 2 * NA; ++a) p[a] += __shfl_xor(p[a], o);
        }
        if (l32 == 0) {
            uint4 sa, da;
            sa.x = pkh(p[0], p[1]);
            sa.y = pkh(p[2], p[3]);
            sa.z = pkh(p[4], 0.0f);
            sa.w = 0u;
            da.x = pkh(p[5] + bb0, p[6] + bb1);
            da.y = pkh(p[7] + bb2, p[8] + bb3);
            da.z = pkh(p[9] + bb4, 0.0f);
            da.w = 0u;
            ushort* r = psd16 + (size_t)n * 16;
            *(uint4*)r       = sa;
            *(uint4*)(r + 8) = da;
        }
    }
}

__global__ void __launch_bounds__(256)
edge_atomic_kernel(const int* __restrict__ ei,
                   const ushort* __restrict__ psd16,
                   unsigned long long* __restrict__ copies,
                   int n_edges, int n_nodes)
{
    const int e = blockIdx.x * blockDim.x + threadIdx.x;
    if (e >= n_edges) return;
    int src = ei[e];
    int dst = ei[n_edges + e];
    src = min(max(src, 0), n_nodes - 1);
    dst = min(max(dst, 0), n_nodes - 1);
    const unsigned long long p64 = edge_pack16(psd16, src, dst);
    __hip_atomic_fetch_add(&copies[(size_t)dst], p64,
                           __ATOMIC_RELAXED, __HIP_MEMORY_SCOPE_AGENT);
}

__global__ void __launch_bounds__(256)
finalize_atomic_kernel(const float* __restrict__ x,
                       const unsigned long long* __restrict__ copies,
                       const float* __restrict__ anchor,
                       float* __restrict__ out, int n_nodes)
{
    __shared__ float sA[NA][IN_DIM];
    __shared__ float sB[8][NA];
    for (int i = threadIdx.x; i < NA * IN_DIM; i += blockDim.x)
        (&sA[0][0])[i] = anchor[i];

    const int node0 = blockIdx.x * 8;
    if (threadIdx.x < 8) {
        const int n = node0 + threadIdx.x;
        if (n < n_nodes) {
            const unsigned long long s = copies[n];
            const float k = 1.0f / QSCALE;
            const float b0 = (float)(unsigned int)(s & 0x3FFF) * k;
            const float b1 = (float)(unsigned int)((s >> 14) & 0x3FFF) * k;
            const float b2 = (float)(unsigned int)((s >> 28) & 0x3FFF) * k;
            const float b3 = (float)(unsigned int)((s >> 42) & 0x3FFF) * k;
            const float fdeg = (float)(unsigned int)(s >> 56);
            const float b4 = fdeg - (b0 + b1 + b2 + b3);
            const float invd = 1.0f / fmaxf(fdeg, 1.0f);
            sB[threadIdx.x][0] = b0 * invd;
            sB[threadIdx.x][1] = b1 * invd;
            sB[threadIdx.x][2] = b2 * invd;
            sB[threadIdx.x][3] = b3 * invd;
            sB[threadIdx.x][4] = b4 * invd;
        }
    }
    __syncthreads();

    const int local = threadIdx.x >> 5;
    const int n = node0 + local;
    if (n >= n_nodes) return;
    const int c = (threadIdx.x & 31) * 4;
    const float b0 = sB[local][0], b1 = sB[local][1], b2 = sB[local][2],
                b3 = sB[local][3], b4 = sB[local][4];
    float4 acc;
    acc.x = b0 * sA[0][c + 0] + b1 * sA[1][c + 0] + b2 * sA[2][c + 0] + b3 * sA[3][c + 0] + b4 * sA[4][c + 0];
    acc.y = b0 * sA[0][c + 1] + b1 * sA[1][c + 1] + b2 * sA[2][c + 1] + b3 * sA[3][c + 1] + b4 * sA[4][c + 1];
    acc.z = b0 * sA[0][c + 2] + b1 * sA[1][c + 2] + b2 * sA[2][c + 2] + b3 * sA[3][c + 2] + b4 * sA[4][c + 2];
    acc.w = b0 * sA[0][c + 3] + b1 * sA[1][c + 3] + b2 * sA[2][c + 3] + b3 * sA[3][c + 3] + b4 * sA[4][c + 3];
    const size_t idx = (size_t)n * (IN_DIM / 4) + (threadIdx.x & 31);
    const float4 xv = ((const float4*)x)[idx];
    float4 ov;
    ov.x = xv.x + acc.x;
    ov.y = xv.y + acc.y;
    ov.z = xv.z + acc.z;
    ov.w = xv.w + acc.w;
    ((float4*)out)[idx] = ov;
}

extern "C" void kernel_launch(void* const* d_in, const int* in_sizes, int n_in,
                              void* d_out, int out_size, void* d_ws, size_t ws_size,
                              hipStream_t stream) {
    const float* x      = (const float*)d_in[0];
    const int*   ei     = (const int*)d_in[1];
    const float* W      = (const float*)d_in[2];
    const float* b_lin  = (const float*)d_in[3];
    const float* anchor = (const float*)d_in[4];
    float* out = (float*)d_out;

    const int n_nodes = in_sizes[0] / IN_DIM;
    const int n_edges = in_sizes[1] / 2;
    const int NB = (n_nodes + BK - 1) / BK;

    // ws layout: psd16 | region | cnt | off | totals
    const size_t psd_b    = (size_t)n_nodes * 16 * sizeof(ushort);
    const size_t region_b = (size_t)NB * CAP * sizeof(unsigned long long);
    const size_t cnt_b    = (size_t)NBLK * NB * sizeof(unsigned int);
    const size_t tot_b    = (size_t)NB * sizeof(unsigned int);

    ushort*             psd16  = (ushort*)d_ws;
    unsigned long long* region = (unsigned long long*)((char*)d_ws + psd_b);
    unsigned int*       cnt    = (unsigned int*)((char*)region + region_b);
    unsigned int*       off    = cnt + (size_t)NBLK * NB;
    unsigned int*       totals = off + (size_t)NBLK * NB;
    const size_t needA = psd_b + region_b + 2 * cnt_b + tot_b;

    if (NB <= MAXNB && ws_size >= needA) {
        node_count_kernel<<<NBLK, 256, 0, stream>>>(x, W, b_lin, ei, psd16, cnt,
                                                    n_nodes, n_edges, NB);
        offset_kernel<<<NB, 256, 0, stream>>>(cnt, off, totals, NB);
        scatter_kernel<<<NBLK, 256, 0, stream>>>(ei, psd16, off, region,
                                                 n_edges, n_nodes, NB);
        reduce_finalize_kernel<<<NB, 256, 0, stream>>>(x, region, totals, anchor,
                                                       out, n_nodes);
    } else {
        unsigned long long* copies = (unsigned long long*)((char*)d_ws + psd_b);
        fill_zero_kernel<<<512, 256, 0, stream>>>(copies, (size_t)n_nodes);
        node_logits_kernel<<<2048, 256, 0, stream>>>(x, W, b_lin, psd16, n_nodes, 2048 * 8);
        edge_atomic_kernel<<<(n_edges + 255) / 256, 256, 0, stream>>>(ei, psd16, copies,
                                                                      n_edges, n_nodes);
        finalize_atomic_kernel<<<(n_nodes + 7) / 8, 256, 0, stream>>>(x, copies, anchor,
                                                                      out, n_nodes);
    }
}

// Round 18
// 53.941 us; speedup vs baseline: 1.0849x; 1.0849x over previous
//
#include <hip/hip_runtime.h>
#include <hip/hip_fp16.h>

#define IN_DIM 128
#define NA 5
#define QSCALE 128.0f      // q fields 14-bit; deg counter at bit 56
#define BK 64              // nodes per bucket
#define CAP 2048           // region capacity per bucket (avg fill ~1024, max ~1150)
#define NBLK 512           // edge slices (must equal 2*256 for offset kernel)
#define MAXNB 1024         // static LDS bound for histograms

typedef __fp16 half2v __attribute__((ext_vector_type(2)));

// psd16[n]: 16 ushorts (32B): [0..4]=s0..s4 (f16), [8..12]=d0..d4+bias (f16)

__device__ __forceinline__ unsigned int pkh(float a, float b) {
    half2v h = __builtin_amdgcn_cvt_pkrtz(a, b);
    return *(unsigned int*)&h;
}
__device__ __forceinline__ float2 uph(unsigned int u) {
    __half2 h = *(__half2*)&u;
    return __half22float2(h);
}

// ---------- softmax+pack from fp16 halves ----------
__device__ __forceinline__ unsigned long long
edge_pack16(const ushort* __restrict__ psd16, int src, int dst)
{
    const uint4 sa = *(const uint4*)(psd16 + (size_t)src * 16);      // s-half (16B)
    const uint4 da = *(const uint4*)(psd16 + (size_t)dst * 16 + 8);  // d-half (16B)
    const float2 s01 = uph(sa.x), s23 = uph(sa.y), s4x = uph(sa.z);
    const float2 d01 = uph(da.x), d23 = uph(da.y), d4x = uph(da.z);

    float l[NA] = { s01.x + d01.x, s01.y + d01.y, s23.x + d23.x,
                    s23.y + d23.y, s4x.x + d4x.x };
    float mx = -INFINITY;
#pragma unroll
    for (int a = 0; a < NA; ++a) {
        l[a] = l[a] > 0.0f ? l[a] : 0.01f * l[a];   // leaky_relu(0.01)
        mx = fmaxf(mx, l[a]);
    }
    float ssum = 0.0f;
#pragma unroll
    for (int a = 0; a < NA; ++a) {
        l[a] = __expf(l[a] - mx);
        ssum += l[a];
    }
    const float inv = __frcp_rn(ssum) * QSCALE;
    const unsigned long long q0 = (unsigned long long)(unsigned int)(l[0] * inv + 0.5f);
    const unsigned long long q1 = (unsigned long long)(unsigned int)(l[1] * inv + 0.5f);
    const unsigned long long q2 = (unsigned long long)(unsigned int)(l[2] * inv + 0.5f);
    const unsigned long long q3 = (unsigned long long)(unsigned int)(l[3] * inv + 0.5f);
    return q0 | (q1 << 14) | (q2 << 28) | (q3 << 42) | (1ull << 56);
}

// ---------- A: fused per-node logits (fdot2, 16-lane groups) + bucket histogram ----------
__global__ void __launch_bounds__(256)
node_count_kernel(const float* __restrict__ x,
                  const float* __restrict__ W,
                  const float* __restrict__ b_lin,
                  const int* __restrict__ ei,
                  ushort* __restrict__ psd16,
                  unsigned int* __restrict__ cnt,   // [slice][bucket]
                  int n_nodes, int n_edges, int NB)
{
    __shared__ unsigned int h[MAXNB];
    for (int i = threadIdx.x; i < NB; i += 256) h[i] = 0u;
    __syncthreads();

    const int j = blockIdx.x;
    {
        const long long e0 = ((long long)j * n_edges) / NBLK;
        const long long e1 = ((long long)(j + 1) * n_edges) / NBLK;
        for (long long e = e0 + threadIdx.x; e < e1; e += 256) {
            int dst = ei[n_edges + e];
            dst = min(max(dst, 0), n_nodes - 1);
            atomicAdd(&h[dst >> 6], 1u);
        }
    }

    // --- node phase: 16-lane groups, lane covers dims [g*8, g*8+8), fdot2 accum ---
    {
        const int g   = threadIdx.x & 15;
        const int grp = (int)((blockIdx.x * blockDim.x + threadIdx.x) >> 4);
        const int total_g = NBLK * 16;

        half2v wh[10][4];
#pragma unroll
        for (int a = 0; a < NA; ++a) {
#pragma unroll
            for (int k = 0; k < 4; ++k) {
                const float* wr = &W[a * 2 * IN_DIM + g * 8 + 2 * k];
                wh[a][k]     = __builtin_amdgcn_cvt_pkrtz(wr[0], wr[1]);
                wh[5 + a][k] = __builtin_amdgcn_cvt_pkrtz(wr[IN_DIM], wr[IN_DIM + 1]);
            }
        }
        const float bb0 = b_lin[0], bb1 = b_lin[1], bb2 = b_lin[2], bb3 = b_lin[3], bb4 = b_lin[4];

        for (int n = grp; n < n_nodes; n += total_g) {
            const float4 xa = *(const float4*)&x[(size_t)n * IN_DIM + g * 8];
            const float4 xb = *(const float4*)&x[(size_t)n * IN_DIM + g * 8 + 4];
            half2v xh[4];
            xh[0] = __builtin_amdgcn_cvt_pkrtz(xa.x, xa.y);
            xh[1] = __builtin_amdgcn_cvt_pkrtz(xa.z, xa.w);
            xh[2] = __builtin_amdgcn_cvt_pkrtz(xb.x, xb.y);
            xh[3] = __builtin_amdgcn_cvt_pkrtz(xb.z, xb.w);

            float p[10];
#pragma unroll
            for (int a = 0; a < 10; ++a) {
                float acc = 0.0f;
#pragma unroll
                for (int k = 0; k < 4; ++k)
                    acc = __builtin_amdgcn_fdot2(xh[k], wh[a][k], acc, false);
                p[a] = acc;
            }
#pragma unroll
            for (int o = 8; o >= 1; o >>= 1) {
#pragma unroll
                for (int a = 0; a < 10; ++a) p[a] += __shfl_xor(p[a], o);
            }
            if (g == 0) {
                uint4 sa, da;
                sa.x = pkh(p[0], p[1]);
                sa.y = pkh(p[2], p[3]);
                sa.z = pkh(p[4], 0.0f);
                sa.w = 0u;
                da.x = pkh(p[5] + bb0, p[6] + bb1);
                da.y = pkh(p[7] + bb2, p[8] + bb3);
                da.z = pkh(p[9] + bb4, 0.0f);
                da.w = 0u;
                ushort* r = psd16 + (size_t)n * 16;
                *(uint4*)r       = sa;
                *(uint4*)(r + 8) = da;
            }
        }
    }

    __syncthreads();
    unsigned int* co = cnt + (size_t)j * NB;
    for (int i = threadIdx.x; i < NB; i += 256) co[i] = h[i];
}

// ---------- B: per-bucket exclusive scan over the 512 slices ----------
__global__ void __launch_bounds__(256)
offset_kernel(const unsigned int* __restrict__ cnt,
              unsigned int* __restrict__ off,
              unsigned int* __restrict__ totals, int NB)
{
    __shared__ unsigned int s[256];
    const int b = blockIdx.x;
    const int t = threadIdx.x;
    const unsigned int c0 = cnt[(size_t)(2 * t) * NB + b];
    const unsigned int c1 = cnt[(size_t)(2 * t + 1) * NB + b];
    const unsigned int pair = c0 + c1;
    s[t] = pair;
    __syncthreads();
#pragma unroll
    for (int d = 1; d < 256; d <<= 1) {
        const unsigned int v = (t >= d) ? s[t - d] : 0u;
        __syncthreads();
        s[t] += v;
        __syncthreads();
    }
    const unsigned int excl = s[t] - pair;
    const unsigned int base = (unsigned int)b * CAP;
    off[(size_t)(2 * t) * NB + b]     = base + excl;
    off[(size_t)(2 * t + 1) * NB + b] = base + excl + c0;
    if (t == 255) totals[b] = s[255];
}

// ---------- C: scatter: softmax + ONE plain u64 store per edge ----------
__global__ void __launch_bounds__(256)
scatter_kernel(const int* __restrict__ ei,
               const ushort* __restrict__ psd16,
               const unsigned int* __restrict__ off,
               unsigned long long* __restrict__ region,
               int n_edges, int n_nodes, int NB)
{
    __shared__ unsigned int o[MAXNB];
    const int j = blockIdx.x;
    const unsigned int* oj = off + (size_t)j * NB;
    for (int i = threadIdx.x; i < NB; i += 256) o[i] = oj[i];
    __syncthreads();

    const long long e0 = ((long long)j * n_edges) / NBLK;
    const long long e1 = ((long long)(j + 1) * n_edges) / NBLK;
    for (long long e = e0 + threadIdx.x; e < e1; e += 256) {
        int dst = ei[n_edges + e];
        int src = ei[e];
        dst = min(max(dst, 0), n_nodes - 1);
        src = min(max(src, 0), n_nodes - 1);
        const int b = dst >> 6;
        const unsigned int pos = atomicAdd(&o[b], 1u);   // LDS counter
        if (pos - (unsigned int)b * CAP < (unsigned int)CAP) {
            const unsigned long long p64 =
                edge_pack16(psd16, src, dst) | ((unsigned long long)(dst & 63) << 57);
            region[pos] = p64;
        }
    }
}

// ---------- D: fused reduce + finalize: one block per bucket (64 nodes) ----------
__global__ void __launch_bounds__(256)
reduce_finalize_kernel(const float* __restrict__ x,
                       const unsigned long long* __restrict__ region,
                       const unsigned int* __restrict__ totals,
                       const float* __restrict__ anchor,
                       float* __restrict__ out, int n_nodes)
{
    __shared__ float sA[NA][IN_DIM];
    __shared__ unsigned long long tab[BK];
    __shared__ float sB[BK][8];

    for (int i = threadIdx.x; i < NA * IN_DIM; i += 256)
        (&sA[0][0])[i] = anchor[i];
    if (threadIdx.x < BK) tab[threadIdx.x] = 0ull;
    __syncthreads();

    const int b = blockIdx.x;
    const unsigned int nt = min(totals[b], (unsigned int)CAP);
    const unsigned long long* rg = region + (size_t)b * CAP;
    const unsigned long long mask = 0x81FFFFFFFFFFFFFFull;   // clear idx bits 57..62
    for (unsigned int i = threadIdx.x; i < nt; i += 256) {
        const unsigned long long e = rg[i];
        atomicAdd(&tab[(unsigned int)(e >> 57) & 63u], e & mask);
    }
    __syncthreads();

    if (threadIdx.x < BK) {
        const unsigned long long s = tab[threadIdx.x];
        const float k = 1.0f / QSCALE;
        const float b0 = (float)(unsigned int)(s & 0x3FFF) * k;
        const float b1 = (float)(unsigned int)((s >> 14) & 0x3FFF) * k;
        const float b2 = (float)(unsigned int)((s >> 28) & 0x3FFF) * k;
        const float b3 = (float)(unsigned int)((s >> 42) & 0x3FFF) * k;
        const float fdeg = (float)(unsigned int)(s >> 56);
        const float b4 = fdeg - (b0 + b1 + b2 + b3);
        const float invd = 1.0f / fmaxf(fdeg, 1.0f);
        sB[threadIdx.x][0] = b0 * invd;
        sB[threadIdx.x][1] = b1 * invd;
        sB[threadIdx.x][2] = b2 * invd;
        sB[threadIdx.x][3] = b3 * invd;
        sB[threadIdx.x][4] = b4 * invd;
    }
    __syncthreads();

    const int l = threadIdx.x & 31;
    const int c = l * 4;
#pragma unroll
    for (int it = 0; it < 8; ++it) {
        const int jn = (threadIdx.x >> 5) + it * 8;      // node within bucket
        const int n = b * BK + jn;
        if (n >= n_nodes) break;
        const float b0 = sB[jn][0], b1 = sB[jn][1], b2 = sB[jn][2],
                    b3 = sB[jn][3], b4 = sB[jn][4];
        float4 acc;
        acc.x = b0 * sA[0][c + 0] + b1 * sA[1][c + 0] + b2 * sA[2][c + 0] + b3 * sA[3][c + 0] + b4 * sA[4][c + 0];
        acc.y = b0 * sA[0][c + 1] + b1 * sA[1][c + 1] + b2 * sA[2][c + 1] + b3 * sA[3][c + 1] + b4 * sA[4][c + 1];
        acc.z = b0 * sA[0][c + 2] + b1 * sA[1][c + 2] + b2 * sA[2][c + 2] + b3 * sA[3][c + 2] + b4 * sA[4][c + 2];
        acc.w = b0 * sA[0][c + 3] + b1 * sA[1][c + 3] + b2 * sA[2][c + 3] + b3 * sA[3][c + 3] + b4 * sA[4][c + 3];

        const size_t idx = (size_t)n * (IN_DIM / 4) + l;
        const float4 xv = ((const float4*)x)[idx];
        float4 ov;
        ov.x = xv.x + acc.x;
        ov.y = xv.y + acc.y;
        ov.z = xv.z + acc.z;
        ov.w = xv.w + acc.w;
        ((float4*)out)[idx] = ov;
    }
}

// ---------- Path B fallback: packed global atomics ----------
__global__ void __launch_bounds__(256)
fill_zero_kernel(unsigned long long* __restrict__ p, size_t n)
{
    size_t i = (size_t)blockIdx.x * blockDim.x + threadIdx.x;
    const size_t stride = (size_t)gridDim.x * blockDim.x;
    for (; i < n; i += stride) p[i] = 0ull;
}

__global__ void __launch_bounds__(256)
node_logits_kernel(const float* __restrict__ x,
                   const float* __restrict__ W,
                   const float* __restrict__ b_lin,
                   ushort* __restrict__ psd16,
                   int n_nodes, int total_hw)
{
    const int l32 = threadIdx.x & 31;
    const int hw0 = (int)((blockIdx.x * blockDim.x + threadIdx.x) >> 5);
    float ws[NA][4], wd[NA][4];
#pragma unroll
    for (int a = 0; a < NA; ++a) {
        const float4 s = *(const float4*)&W[a * 2 * IN_DIM + l32 * 4];
        const float4 d = *(const float4*)&W[a * 2 * IN_DIM + IN_DIM + l32 * 4];
        ws[a][0] = s.x; ws[a][1] = s.y; ws[a][2] = s.z; ws[a][3] = s.w;
        wd[a][0] = d.x; wd[a][1] = d.y; wd[a][2] = d.z; wd[a][3] = d.w;
    }
    const float bb0 = b_lin[0], bb1 = b_lin[1], bb2 = b_lin[2], bb3 = b_lin[3], bb4 = b_lin[4];
    for (int n = hw0; n < n_nodes; n += total_hw) {
        const float4 xv = *(const float4*)&x[(size_t)n * IN_DIM + l32 * 4];
        float p[2 * NA];
#pragma unroll
        for (int a = 0; a < NA; ++a) {
            p[a]      = xv.x * ws[a][0] + xv.y * ws[a][1] + xv.z * ws[a][2] + xv.w * ws[a][3];
            p[NA + a] = xv.x * wd[a][0] + xv.y * wd[a][1] + xv.z * wd[a][2] + xv.w * wd[a][3];
        }
#pragma unroll
        for (int o = 16; o >= 1; o >>= 1) {
#pragma unroll
            for (int a = 0; a < 2 * NA; ++a) p[a] += __shfl_xor(p[a], o);
        }
        if (l32 == 0) {
            uint4 sa, da;
            sa.x = pkh(p[0], p[1]);
            sa.y = pkh(p[2], p[3]);
            sa.z = pkh(p[4], 0.0f);
            sa.w = 0u;
            da.x = pkh(p[5] + bb0, p[6] + bb1);
            da.y = pkh(p[7] + bb2, p[8] + bb3);
            da.z = pkh(p[9] + bb4, 0.0f);
            da.w = 0u;
            ushort* r = psd16 + (size_t)n * 16;
            *(uint4*)r       = sa;
            *(uint4*)(r + 8) = da;
        }
    }
}

__global__ void __launch_bounds__(256)
edge_atomic_kernel(const int* __restrict__ ei,
                   const ushort* __restrict__ psd16,
                   unsigned long long* __restrict__ copies,
                   int n_edges, int n_nodes)
{
    const int e = blockIdx.x * blockDim.x + threadIdx.x;
    if (e >= n_edges) return;
    int src = ei[e];
    int dst = ei[n_edges + e];
    src = min(max(src, 0), n_nodes - 1);
    dst = min(max(dst, 0), n_nodes - 1);
    const unsigned long long p64 = edge_pack16(psd16, src, dst);
    __hip_atomic_fetch_add(&copies[(size_t)dst], p64,
                           __ATOMIC_RELAXED, __HIP_MEMORY_SCOPE_AGENT);
}

__global__ void __launch_bounds__(256)
finalize_atomic_kernel(const float* __restrict__ x,
                       const unsigned long long* __restrict__ copies,
                       const float* __restrict__ anchor,
                       float* __restrict__ out, int n_nodes)
{
    __shared__ float sA[NA][IN_DIM];
    __shared__ float sB[8][NA];
    for (int i = threadIdx.x; i < NA * IN_DIM; i += blockDim.x)
        (&sA[0][0])[i] = anchor[i];

    const int node0 = blockIdx.x * 8;
    if (threadIdx.x < 8) {
        const int n = node0 + threadIdx.x;
        if (n < n_nodes) {
            const unsigned long long s = copies[n];
            const float k = 1.0f / QSCALE;
            const float b0 = (float)(unsigned int)(s & 0x3FFF) * k;
            const float b1 = (float)(unsigned int)((s >> 14) & 0x3FFF) * k;
            const float b2 = (float)(unsigned int)((s >> 28) & 0x3FFF) * k;
            const float b3 = (float)(unsigned int)((s >> 42) & 0x3FFF) * k;
            const float fdeg = (float)(unsigned int)(s >> 56);
            const float b4 = fdeg - (b0 + b1 + b2 + b3);
            const float invd = 1.0f / fmaxf(fdeg, 1.0f);
            sB[threadIdx.x][0] = b0 * invd;
            sB[threadIdx.x][1] = b1 * invd;
            sB[threadIdx.x][2] = b2 * invd;
            sB[threadIdx.x][3] = b3 * invd;
            sB[threadIdx.x][4] = b4 * invd;
        }
    }
    __syncthreads();

    const int local = threadIdx.x >> 5;
    const int n = node0 + local;
    if (n >= n_nodes) return;
    const int c = (threadIdx.x & 31) * 4;
    const float b0 = sB[local][0], b1 = sB[local][1], b2 = sB[local][2],
                b3 = sB[local][3], b4 = sB[local][4];
    float4 acc;
    acc.x = b0 * sA[0][c + 0] + b1 * sA[1][c + 0] + b2 * sA[2][c + 0] + b3 * sA[3][c + 0] + b4 * sA[4][c + 0];
    acc.y = b0 * sA[0][c + 1] + b1 * sA[1][c + 1] + b2 * sA[2][c + 1] + b3 * sA[3][c + 1] + b4 * sA[4][c + 1];
    acc.z = b0 * sA[0][c + 2] + b1 * sA[1][c + 2] + b2 * sA[2][c + 2] + b3 * sA[3][c + 2] + b4 * sA[4][c + 2];
    acc.w = b0 * sA[0][c + 3] + b1 * sA[1][c + 3] + b2 * sA[2][c + 3] + b3 * sA[3][c + 3] + b4 * sA[4][c + 3];
    const size_t idx = (size_t)n * (IN_DIM / 4) + (threadIdx.x & 31);
    const float4 xv = ((const float4*)x)[idx];
    float4 ov;
    ov.x = xv.x + acc.x;
    ov.y = xv.y + acc.y;
    ov.z = xv.z + acc.z;
    ov.w = xv.w + acc.w;
    ((float4*)out)[idx] = ov;
}

extern "C" void kernel_launch(void* const* d_in, const int* in_sizes, int n_in,
                              void* d_out, int out_size, void* d_ws, size_t ws_size,
                              hipStream_t stream) {
    const float* x      = (const float*)d_in[0];
    const int*   ei     = (const int*)d_in[1];
    const float* W      = (const float*)d_in[2];
    const float* b_lin  = (const float*)d_in[3];
    const float* anchor = (const float*)d_in[4];
    float* out = (float*)d_out;

    const int n_nodes = in_sizes[0] / IN_DIM;
    const int n_edges = in_sizes[1] / 2;
    const int NB = (n_nodes + BK - 1) / BK;

    // ws layout: psd16 | region | cnt | off | totals
    const size_t psd_b    = (size_t)n_nodes * 16 * sizeof(ushort);
    const size_t region_b = (size_t)NB * CAP * sizeof(unsigned long long);
    const size_t cnt_b    = (size_t)NBLK * NB * sizeof(unsigned int);
    const size_t tot_b    = (size_t)NB * sizeof(unsigned int);

    ushort*             psd16  = (ushort*)d_ws;
    unsigned long long* region = (unsigned long long*)((char*)d_ws + psd_b);
    unsigned int*       cnt    = (unsigned int*)((char*)region + region_b);
    unsigned int*       off    = cnt + (size_t)NBLK * NB;
    unsigned int*       totals = off + (size_t)NBLK * NB;
    const size_t needA = psd_b + region_b + 2 * cnt_b + tot_b;

    if (NB <= MAXNB && ws_size >= needA) {
        node_count_kernel<<<NBLK, 256, 0, stream>>>(x, W, b_lin, ei, psd16, cnt,
                                                    n_nodes, n_edges, NB);
        offset_kernel<<<NB, 256, 0, stream>>>(cnt, off, totals, NB);
        scatter_kernel<<<NBLK, 256, 0, stream>>>(ei, psd16, off, region,
                                                 n_edges, n_nodes, NB);
        reduce_finalize_kernel<<<NB, 256, 0, stream>>>(x, region, totals, anchor,
                                                       out, n_nodes);
    } else {
        unsigned long long* copies = (unsigned long long*)((char*)d_ws + psd_b);
        fill_zero_kernel<<<512, 256, 0, stream>>>(copies, (size_t)n_nodes);
        node_logits_kernel<<<2048, 256, 0, stream>>>(x, W, b_lin, psd16, n_nodes, 2048 * 8);
        edge_atomic_kernel<<<(n_edges + 255) / 256, 256, 0, stream>>>(ei, psd16, copies,
                                                                      n_edges, n_nodes);
        finalize_atomic_kernel<<<(n_nodes + 7) / 8, 256, 0, stream>>>(x, copies, anchor,
                                                                      out, n_nodes);
    }
}